// Round 1
// 148.857 us; speedup vs baseline: 1.0128x; 1.0128x over previous
//
#include <hip/hip_runtime.h>
#include <hip/hip_bf16.h>

// ---------------------------------------------------------------------------
// NaiveFourierKANLayer as GEMM:  y = [cos|sin features][4096 x 32768] * W + b
// R10: (a) coalesced prep (one block per i, 256B-run reads + LDS transpose)
//      -- old prep read fc in 32B granules at 64KB stride (~60us est).
//      (b) wave tile 32r x 256c (was 64r x 128c): kills the by-split's 2x
//      chip-wide duplication of A-synthesis VALU; MFMA/wave/iter unchanged.
//      Block = 256r x 256c, 8 waves, SPLITK=16, grid 256. LDS 144KB.
//      A-synth math byte-identical to verified R5-R9 code.
// ---------------------------------------------------------------------------

typedef __attribute__((ext_vector_type(8))) short short8;
typedef __attribute__((ext_vector_type(4))) float f32x4;

#define SPLITK 16
#define ICHUNK (256 / SPLITK)   // 16 i's per block

#define INV2PI 0.15915494309189535f

// ---- bf16 pack helpers ----
__device__ __forceinline__ unsigned short f2bf(float f) {
    unsigned u = __builtin_bit_cast(unsigned, f);
    u += 0x7fffu + ((u >> 16) & 1u);
    return (unsigned short)(u >> 16);
}
#if __has_builtin(__builtin_amdgcn_cvt_pk_bf16_f32)
typedef __attribute__((ext_vector_type(2))) __bf16 bf16x2_t;
__device__ __forceinline__ unsigned pkbf16(float a, float b) {
    bf16x2_t v = __builtin_amdgcn_cvt_pk_bf16_f32(a, b);
    return __builtin_bit_cast(unsigned, v);
}
#else
__device__ __forceinline__ unsigned pkbf16(float a, float b) {
    unsigned ua = __builtin_bit_cast(unsigned, a) + 0x8000u;
    unsigned ub = __builtin_bit_cast(unsigned, b) + 0x8000u;
    return __builtin_amdgcn_perm(ub, ua, 0x07060302u);  // [b.hi16 | a.hi16]
}
#endif

__device__ __forceinline__ void dbl2(float c, float s, float& co, float& so) {
    float t = c + c;
    co = __builtin_fmaf(t, c, -1.f);
    so = t * s;
}
__device__ __forceinline__ void rot2(float c, float s, float cr, float sr,
                                     float& co, float& so) {
    float t = s * sr;
    co = __builtin_fmaf(c, cr, -t);
    float u = s * cr;
    so = __builtin_fmaf(c, sr, u);
}

// 8 consecutive harmonics from seeds f_{-1}, f_0 with multiplier m1=2cos(x)
__device__ __forceinline__ short8 chain8(float m1, float fm1, float f0) {
    unsigned r[4];
    float vp = fm1, v = f0;
    #pragma unroll
    for (int h = 0; h < 4; ++h) {
        float v1 = __builtin_fmaf(m1, v, -vp);
        r[h] = pkbf16(v, v1);
        float v2 = __builtin_fmaf(m1, v1, -v);
        vp = v1; v = v2;
    }
    uint4 u; u.x = r[0]; u.y = r[1]; u.z = r[2]; u.w = r[3];
    return __builtin_bit_cast(short8, u);
}

// async 16B global->LDS
__device__ __forceinline__ void async_load16(const void* g, void* l) {
    __builtin_amdgcn_global_load_lds(
        (const __attribute__((address_space(1))) unsigned int*)g,
        (__attribute__((address_space(3))) unsigned int*)l,
        16, 0, 0);
}

// ---------------------------------------------------------------------------
// prep: one block per i. Reads fc[tt][o][i][0:64] as 256B-contiguous runs
// (16 lanes x float4 per run -> fully coalesced), packs bf16 pairs through a
// bank-padded LDS transpose, writes the 64KB/i coeff image contiguously.
// Image layout (per i, 4096 uint4): gi -> sog=gi>>6, ll=gi&63; s=sog>>4,
// og=sog&15; o=og*16+(ll&15); k=s*32+(ll>>4)*8; tt=k>>6, g=k&63.
// ---------------------------------------------------------------------------
__global__ __launch_bounds__(512) void prep_kernel(
    const float* __restrict__ fc, unsigned short* __restrict__ ws2)
{
    __shared__ unsigned pk[512][36];   // row = tt*256+o, col = g/2; pad 32->36
    const int i = blockIdx.x;          // 0..255
    const int t = threadIdx.x;         // 0..511
    const int rr  = t >> 4;            // run-in-pass 0..31
    const int l16 = t & 15;

    #pragma unroll
    for (int p = 0; p < 16; ++p) {
        int r = p * 32 + rr;           // (tt*256+o)
        const float4* src =
            (const float4*)(fc + ((size_t)r * 256 + i) * 64) + l16;
        float4 v = *src;               // g = l16*4 .. +3
        pk[r][l16 * 2]     = pkbf16(v.x, v.y);
        pk[r][l16 * 2 + 1] = pkbf16(v.z, v.w);
    }
    __syncthreads();

    #pragma unroll
    for (int gg = 0; gg < 8; ++gg) {
        int gi = gg * 512 + t;
        int sog = gi >> 6, ll = gi & 63;
        int s = sog >> 4, og = sog & 15;
        int o = og * 16 + (ll & 15);
        int k = s * 32 + (ll >> 4) * 8;
        int tt = k >> 6, g = k & 63;
        int r = tt * 256 + o;
        int c = g >> 1;                // multiple of 4 -> 16B-aligned read
        uint4 v;
        v.x = pk[r][c]; v.y = pk[r][c + 1];
        v.z = pk[r][c + 2]; v.w = pk[r][c + 3];
        ((uint4*)ws2)[(size_t)i * 4096 + gi] = v;
    }
}

// out = bias (for atomic-fallback paths)
__global__ __launch_bounds__(256) void bias_init(
    const float* __restrict__ bias, float* __restrict__ out)
{
    int idx4 = blockIdx.x * 256 + threadIdx.x;   // 0..262143
    ((float4*)out)[idx4] = ((const float4*)bias)[idx4 & 63];
}

// out = bias + sum_z bf16partial[z]
__global__ __launch_bounds__(256) void reduce_kernel(
    const unsigned short* __restrict__ pws, const float* __restrict__ bias,
    float* __restrict__ out)
{
    int idx4 = blockIdx.x * 256 + threadIdx.x;   // 0..262143 float4s
    float4 r = ((const float4*)bias)[idx4 & 63];
    #pragma unroll
    for (int z = 0; z < SPLITK; ++z) {
        ushort4 v = ((const ushort4*)pws)[(size_t)z * 262144 + idx4];
        r.x += __builtin_bit_cast(float, (unsigned)v.x << 16);
        r.y += __builtin_bit_cast(float, (unsigned)v.y << 16);
        r.z += __builtin_bit_cast(float, (unsigned)v.z << 16);
        r.w += __builtin_bit_cast(float, (unsigned)v.w << 16);
    }
    ((float4*)out)[idx4] = r;
}

template <bool USE_WS, bool PARTIAL>
__global__ __launch_bounds__(512, 2) void fkan_gemm(
    const float* __restrict__ x, const float* __restrict__ fc,
    const unsigned short* __restrict__ bws, float* __restrict__ out,
    unsigned short* __restrict__ pws)
{
    __shared__ uint4 Bimg[2][4096];        // 128 KB: full-N coeff image, dbuf
    __shared__ float xs[ICHUNK][256];      // 16 KB: x[i][row] transposed

    const int t  = threadIdx.x;            // 0..511
    const int l  = t & 63;
    const int w  = t >> 6;                 // row-wave 0..7 (32 rows each)
    const int q  = l >> 4;                 // MFMA quad -> k offset 8q
    const int m  = l & 15;                 // MFMA row within 16

    // z in low 4 bits -> blocks sharing a B i-window land on one XCD (z%8)
    const int bid = blockIdx.x;
    const int z   = bid & 15;
    const int bx  = bid >> 4;              // 0..15
    const int rowBase = bx * 256;
    const int iBase   = z * ICHUNK;

    f32x4 acc[2][16];
    #pragma unroll
    for (int a = 0; a < 2; ++a)
        #pragma unroll
        for (int b = 0; b < 16; ++b) acc[a][b] = (f32x4)0.0f;

    auto stageB = [&](int p, int i) {
        if (USE_WS) {
            const uint4* base = (const uint4*)bws + (size_t)i * 4096;
            #pragma unroll
            for (int cc = 0; cc < 8; ++cc) {
                int c = cc * 8 + w;                 // wave-uniform chunk id
                async_load16(base + (size_t)c * 64 + l, (void*)(&Bimg[p][c * 64]));
            }
        } else {
            #pragma unroll
            for (int gg = 0; gg < 8; ++gg) {
                int gi  = gg * 512 + t;
                int sog = gi >> 6, ll = gi & 63;
                int s = sog >> 4, ogb = sog & 15;
                int o = ogb * 16 + (ll & 15);
                int k = s * 32 + (ll >> 4) * 8;
                int tt = k >> 6, g = k & 63;
                const float4* p4 = (const float4*)(fc +
                    ((((size_t)tt * 256 + o) * 256 + i) * 64 + g));
                float4 a = p4[0], b = p4[1];
                uint4 v;
                v.x = pkbf16(a.x, a.y); v.y = pkbf16(a.z, a.w);
                v.z = pkbf16(b.x, b.y); v.w = pkbf16(b.z, b.w);
                Bimg[p][gi] = v;
            }
        }
    };

    // ---- preamble: stage B(iter0) + x tile, one barrier ----
    stageB(0, iBase);
    {
        const int row = t >> 1;
        const int hf  = t & 1;
        const float4* px =
            (const float4*)(x + (size_t)(rowBase + row) * 256 + iBase) + hf * 2;
        float4 v0 = px[0], v1 = px[1];
        int c0 = hf * 8;
        xs[c0 + 0][row] = v0.x; xs[c0 + 1][row] = v0.y;
        xs[c0 + 2][row] = v0.z; xs[c0 + 3][row] = v0.w;
        xs[c0 + 4][row] = v1.x; xs[c0 + 5][row] = v1.y;
        xs[c0 + 6][row] = v1.z; xs[c0 + 7][row] = v1.w;
    }
    __syncthreads();

    #pragma unroll 1
    for (int ii = 0; ii < ICHUNK; ++ii) {
        const int p = ii & 1;

        // 1. async-stage next B into the other buffer (in flight during 2-3)
        if (ii + 1 < ICHUNK) stageB(p ^ 1, iBase + ii + 1);

        // 2. synthesize A fragments in registers (verified R5 math, verbatim)
        short8 aF[2][4];   // [rf][s]
        #pragma unroll
        for (int rf = 0; rf < 2; ++rf) {
            float xv = xs[ii][w * 32 + rf * 16 + m];
            float rev = xv * INV2PI;
            float s1 = __builtin_amdgcn_sinf(rev);
            float c1 = __builtin_amdgcn_cosf(rev);
            const float m1 = c1 + c1;
            float c2, s2, c4, s4, c8, s8, c16, s16, c32, s32;
            dbl2(c1, s1, c2, s2);
            dbl2(c2, s2, c4, s4);
            dbl2(c4, s4, c8, s8);
            dbl2(c8, s8, c16, s16);
            dbl2(c16, s16, c32, s32);
            float c24, s24;
            rot2(c16, s16, c8, s8, c24, s24);
            float cq = (q == 0) ? 1.f : (q == 1) ? c8 : (q == 2) ? c16 : c24;
            float sq = (q == 0) ? 0.f : (q == 1) ? s8 : (q == 2) ? s16 : s24;
            float cq1, sq1, cB, sB, cB1, sB1;
            rot2(cq, sq, c1, s1, cq1, sq1);     // 8q+1
            rot2(cq, sq, c32, s32, cB, sB);     // 8q+32
            rot2(cB, sB, c1, s1, cB1, sB1);     // 8q+33
            aF[rf][0] = chain8(m1, cq, cq1);    // cos, freq 8q+1..8q+8
            aF[rf][1] = chain8(m1, cB, cB1);    // cos, freq 8q+33..
            aF[rf][2] = chain8(m1, sq, sq1);    // sin, freq 8q+1..
            aF[rf][3] = chain8(m1, sB, sB1);    // sin, freq 8q+33..
        }

        // 3. MFMA: per (s, col-half), read 8 B-fragments then 16 MFMAs
        #pragma unroll
        for (int s = 0; s < 4; ++s) {
            #pragma unroll
            for (int hf = 0; hf < 2; ++hf) {
                short8 bF[8];
                #pragma unroll
                for (int cf = 0; cf < 8; ++cf)
                    bF[cf] = __builtin_bit_cast(short8,
                        Bimg[p][(s * 16 + hf * 8 + cf) * 64 + l]);
                #pragma unroll
                for (int rf = 0; rf < 2; ++rf)
                    #pragma unroll
                    for (int cf = 0; cf < 8; ++cf)
                        acc[rf][hf * 8 + cf] =
                            __builtin_amdgcn_mfma_f32_16x16x32_bf16(
                                aF[rf][s], bF[cf], acc[rf][hf * 8 + cf], 0, 0, 0);
            }
        }

        // 4. one barrier: vmcnt drain covered by steps 2-3
        __syncthreads();
    }

    // epilogue: C/D layout col=l&15, row=(l>>4)*4+e
    const int r0 = rowBase + w * 32 + (l >> 4) * 4;
    if (PARTIAL) {
        unsigned short* dst = pws + (size_t)z * (4096u * 256u);
        #pragma unroll
        for (int rf = 0; rf < 2; ++rf)
            #pragma unroll
            for (int cf = 0; cf < 16; ++cf)
                #pragma unroll
                for (int e = 0; e < 4; ++e)
                    dst[(size_t)(r0 + rf * 16 + e) * 256 + (cf * 16 + m)] =
                        f2bf(acc[rf][cf][e]);
    } else {
        #pragma unroll
        for (int rf = 0; rf < 2; ++rf)
            #pragma unroll
            for (int cf = 0; cf < 16; ++cf)
                #pragma unroll
                for (int e = 0; e < 4; ++e)
                    atomicAdd(out + (size_t)(r0 + rf * 16 + e) * 256 + (cf * 16 + m),
                              acc[rf][cf][e]);
    }
}

extern "C" void kernel_launch(void* const* d_in, const int* in_sizes, int n_in,
                              void* d_out, int out_size, void* d_ws, size_t ws_size,
                              hipStream_t stream) {
    const float* x    = (const float*)d_in[0];
    const float* fc   = (const float*)d_in[1];
    const float* bias = (const float*)d_in[2];
    float* out = (float*)d_out;
    unsigned short* bws = (unsigned short*)d_ws;

    const size_t wsCoeff = (size_t)256 * 4096 * 16;                     // 16.78 MB
    const size_t wsFull  = wsCoeff + (size_t)SPLITK * 4096 * 256 * 2;   // +33.55 MB bf16 partials
    unsigned short* pws = (unsigned short*)((char*)d_ws + wsCoeff);

    if (ws_size >= wsFull) {
        hipLaunchKernelGGL(prep_kernel, dim3(256), dim3(512), 0, stream, fc, bws);
        hipLaunchKernelGGL((fkan_gemm<true, true>), dim3(256), dim3(512), 0, stream,
                           x, fc, bws, out, pws);
        hipLaunchKernelGGL(reduce_kernel, dim3(1024), dim3(256), 0, stream,
                           pws, bias, out);
    } else if (ws_size >= wsCoeff) {
        hipLaunchKernelGGL(bias_init, dim3(1024), dim3(256), 0, stream, bias, out);
        hipLaunchKernelGGL(prep_kernel, dim3(256), dim3(512), 0, stream, fc, bws);
        hipLaunchKernelGGL((fkan_gemm<true, false>), dim3(256), dim3(512), 0, stream,
                           x, fc, bws, out, pws);
    } else {
        hipLaunchKernelGGL(bias_init, dim3(1024), dim3(256), 0, stream, bias, out);
        hipLaunchKernelGGL((fkan_gemm<false, false>), dim3(256), dim3(512), 0, stream,
                           x, fc, bws, out, pws);
    }
}